// Round 17
// baseline (412.471 us; speedup 1.0000x reference)
//
#include <hip/hip_runtime.h>
#include <hip/hip_bf16.h>

// Problem constants
#define NPTS   65536
#define CCH    384
#define NH     6
#define DH     64
#define KP     256   // patch size
#define NPATCH 256   // NPTS / KP
#define PB     20    // POS_BND
#define RNUM   41    // 2*PB+1
#define K1     384   // GEMM inner dim

typedef float f32x4 __attribute__((ext_vector_type(4)));
typedef short s16x8 __attribute__((ext_vector_type(8)));
typedef short s16x4 __attribute__((ext_vector_type(4)));
typedef unsigned u32x4 __attribute__((ext_vector_type(4)));
typedef unsigned short u16;
typedef u16 u16x4 __attribute__((ext_vector_type(4)));

static __device__ __forceinline__ u16 f2b(float f) {
    union { __hip_bfloat16 h; u16 u; } cv;
    cv.h = __float2bfloat16(f);
    return cv.u;
}
static __device__ __forceinline__ float b2f(u16 u) {
    union { float f; unsigned v; } cv; cv.v = ((unsigned)u) << 16; return cv.f;
}
static __device__ __forceinline__ void split1(float x, u16& h, u16& l) {
    h = f2b(x);
    l = f2b(x - b2f(h));
}

typedef __attribute__((address_space(3))) unsigned lds_u;
typedef const __attribute__((address_space(1))) unsigned glob_u;
static __device__ __forceinline__ void gll16(const void* g, void* l) {
    __builtin_amdgcn_global_load_lds((glob_u*)g, (lds_u*)l, 16, 0, 0);
}

// ---------------------------------------------------------------------------
// Prep kernels
// ---------------------------------------------------------------------------
__global__ __launch_bounds__(256) void split_arr(
    const float* __restrict__ s, u16* __restrict__ h, u16* __restrict__ l, int n4)
{
    int i = blockIdx.x * 256 + threadIdx.x;
    if (i >= n4) return;
    float4 v = ((const float4*)s)[i];
    u16 h0, l0, h1, l1, h2, l2, h3, l3;
    split1(v.x, h0, l0); split1(v.y, h1, l1);
    split1(v.z, h2, l2); split1(v.w, h3, l3);
    u16x4 hv, lv;
    hv[0] = h0; hv[1] = h1; hv[2] = h2; hv[3] = h3;
    lv[0] = l0; lv[1] = l1; lv[2] = l2; lv[3] = l3;
    *(u16x4*)&h[(size_t)i * 4] = hv;
    *(u16x4*)&l[(size_t)i * 4] = lv;
}

// Gather fh = bf16(feat[order[j]]) only
__global__ __launch_bounds__(256) void gather_h(
    const float* __restrict__ feat, const int* __restrict__ order,
    u16* __restrict__ fh)
{
    int i = blockIdx.x * 256 + threadIdx.x;   // over NPTS*96 float4s
    int r = i / 96, c4 = i % 96;
    int o = order[r];
    float4 v = *((const float4*)(feat + (size_t)o * CCH) + c4);
    u16x4 hv;
    hv[0] = f2b(v.x); hv[1] = f2b(v.y); hv[2] = f2b(v.z); hv[3] = f2b(v.w);
    *(u16x4*)&fh[(size_t)r * CCH + c4 * 4] = hv;
}

__global__ __launch_bounds__(256) void pack_coords(
    const int* __restrict__ order, const int* __restrict__ gcoord,
    unsigned* __restrict__ cpk_g)
{
    int j = blockIdx.x * 256 + threadIdx.x;
    int o = order[j];
    const int* gc = gcoord + (size_t)o * 3;
    cpk_g[j] = (unsigned)gc[0] | ((unsigned)gc[1] << 10) | ((unsigned)gc[2] << 20);
}

// ---------------------------------------------------------------------------
// Kernel A: 2-term split GEMM (qkv): C = Ah*Bh + Ah*Bl
// 2-phase pipeline (T3 minimum): A double-buffered in LDS (2x16 KB, chunk-XOR
// source-swizzled); B fragments read DIRECT from global (1.7 MB, L2-resident
// via XCD swizzle). Per iter: STAGE(next) -> compute(cur) -> barrier.
// ---------------------------------------------------------------------------
#define STAGE_A(kc_, buf_)                                              \
    {                                                                   \
        _Pragma("unroll")                                               \
        for (int i_ = 0; i_ < 4; ++i_) {                                \
            int ci_ = i_ * 256 + t;                                     \
            int r_ = ci_ >> 3, j_ = ci_ & 7;                            \
            int c8_ = (j_ ^ (r_ & 7)) * 8;                              \
            gll16(Ah + (size_t)(m0 + r_) * K1 + (kc_) + c8_,            \
                  &ldsA[buf_][ci_ * 8]);                                \
        }                                                               \
    }

__global__ __launch_bounds__(256, 3) void gemm_qkv(
    const u16* __restrict__ Ah,
    const u16* __restrict__ Bh, const u16* __restrict__ Bl,
    const float* __restrict__ bias,
    u16* __restrict__ q_out, u16* __restrict__ k_out, u16* __restrict__ vt_out)
{
    __shared__ __align__(16) u16 ldsA[2][128 * 64];   // 32 KB

    const int t = threadIdx.x;
    const int lane = t & 63, wv = t >> 6;
    const int L = lane & 15, gq = lane >> 4;
    const int wr = wv >> 1, wc = wv & 1;

    const int orig = blockIdx.y * 9 + blockIdx.x;          // linear, x fastest
    const int swz  = (orig & 7) * 576 + (orig >> 3);        // bijective (4608%8==0)
    const int n0 = (swz % 9) * 128;
    const int m0 = (swz / 9) * 128;

    f32x4 acc[4][4];
#pragma unroll
    for (int mi = 0; mi < 4; ++mi)
#pragma unroll
        for (int ni = 0; ni < 4; ++ni) acc[mi][ni] = (f32x4)0.f;

    STAGE_A(0, 0);
    __syncthreads();

    for (int step = 0; step < 6; ++step) {
        const int kc = step * 64;
        if (step < 5) STAGE_A(kc + 64, (step + 1) & 1);
        const u16* LA = ldsA[step & 1];
#pragma unroll
        for (int ks = 0; ks < 2; ++ks) {
            s16x8 fah[4], fbh[4], fbl[4];
            const int ko = kc + ks * 32 + gq * 8;
#pragma unroll
            for (int x = 0; x < 4; ++x) {
                int arow = wr * 64 + x * 16 + L;
                int brow = n0 + wc * 64 + x * 16 + L;
                int ka = ((ks * 4 + gq) ^ (arow & 7)) * 8;
                fah[x] = *(const s16x8*)&LA[arow * 64 + ka];
                fbh[x] = *(const s16x8*)&Bh[(size_t)brow * K1 + ko];
                fbl[x] = *(const s16x8*)&Bl[(size_t)brow * K1 + ko];
            }
#pragma unroll
            for (int mi = 0; mi < 4; ++mi)
#pragma unroll
                for (int ni = 0; ni < 4; ++ni) {
                    acc[mi][ni] = __builtin_amdgcn_mfma_f32_16x16x32_bf16(
                        fah[mi], fbh[ni], acc[mi][ni], 0, 0, 0);
                    acc[mi][ni] = __builtin_amdgcn_mfma_f32_16x16x32_bf16(
                        fah[mi], fbl[ni], acc[mi][ni], 0, 0, 0);
                }
        }
        __syncthreads();
    }

    float bfrag[4];
#pragma unroll
    for (int ni = 0; ni < 4; ++ni) bfrag[ni] = bias[n0 + wc * 64 + ni * 16 + L];

    const int cq   = n0 + wc * 64;
    const int ssel = cq / CCH;
    const int hh   = (cq % CCH) / DH;

    if (ssel == 2) {
#pragma unroll
        for (int mi = 0; mi < 4; ++mi) {
            int jb = m0 + wr * 64 + mi * 16;
            int p = jb >> 8, kr0 = (jb & 255) + gq * 4;
            size_t hb = (size_t)(p * NH + hh) * DH;
#pragma unroll
            for (int ni = 0; ni < 4; ++ni) {
                int d = ni * 16 + L;
                u16x4 w;
#pragma unroll
                for (int reg = 0; reg < 4; ++reg)
                    w[reg] = f2b(acc[mi][ni][reg] + bfrag[ni]);
                int kswz = (kr0 & ~63) + ((kr0 & 63) ^ ((d & 7) << 3));
                *(u16x4*)&vt_out[(hb + d) * KP + kswz] = w;
            }
        }
    } else if (ssel == 1) {
#pragma unroll
        for (int mi = 0; mi < 4; ++mi)
#pragma unroll
            for (int reg = 0; reg < 4; ++reg) {
                int j = m0 + wr * 64 + mi * 16 + gq * 4 + reg;
                int kk = j & 255;
                u16* orow = k_out + ((size_t)((j >> 8) * NH + hh) * KP + kk) * DH;
                int sw = (kk & 7) << 3;
#pragma unroll
                for (int ni = 0; ni < 4; ++ni)
                    orow[(ni * 16 + L) ^ sw] = f2b(acc[mi][ni][reg] + bfrag[ni]);
            }
    } else {
#pragma unroll
        for (int mi = 0; mi < 4; ++mi)
#pragma unroll
            for (int reg = 0; reg < 4; ++reg) {
                int j = m0 + wr * 64 + mi * 16 + gq * 4 + reg;
                u16* orow = q_out + ((size_t)((j >> 8) * NH + hh) * KP + (j & 255)) * DH;
#pragma unroll
                for (int ni = 0; ni < 4; ++ni)
                    orow[ni * 16 + L] = f2b((acc[mi][ni][reg] + bfrag[ni]) * 0.125f);
            }
    }
}

// ---------------------------------------------------------------------------
// Kernel B: swapped-operand MFMA flash attention per (patch, head).
// 8 waves x 32 q-rows (512 threads). Frozen from R12.
// ---------------------------------------------------------------------------
#define LDSK 0
#define LDSV 8192
#define CPKO 16384
#define RPEO 17408
#define SMEMSZ 35328          // epilogue: 8 waves x 4352B transpose buffers

__global__ __launch_bounds__(512, 4) void attn_mfma(
    const u16* __restrict__ q_s, const u16* __restrict__ k_s,
    const u16* __restrict__ vt_s, const unsigned* __restrict__ cpk_g,
    const float* __restrict__ rpe_table, unsigned* __restrict__ oa32)
{
    __shared__ __align__(16) unsigned char smem[SMEMSZ];
    unsigned* cpk  = (unsigned*)&smem[CPKO];
    float*    rpes = (float*)&smem[RPEO];

    const int t    = threadIdx.x;
    const int p    = blockIdx.x, h = blockIdx.y;
    const int lane = t & 63, wv = t >> 6;
    const int L    = lane & 15, gq = lane >> 4;
    const int q0   = wv * 32;
    const size_t base = (size_t)(p * NH + h) * KP * DH;

    if (t < KP) cpk[t] = cpk_g[p * KP + t];
    if (t >= KP && t < KP + 3 * RNUM) rpes[t - KP] = rpe_table[(t - KP) * NH + h];
    __syncthreads();

    int qx[2], qy[2], qz[2];
#pragma unroll
    for (int qi = 0; qi < 2; ++qi) {
        unsigned c = cpk[q0 + qi * 16 + L];
        qx[qi] = (int)(c & 1023u);
        qy[qi] = (int)((c >> 10) & 1023u);
        qz[qi] = (int)(c >> 20);
    }

    s16x8 aq[2][2];
#pragma unroll
    for (int qi = 0; qi < 2; ++qi)
#pragma unroll
        for (int ks = 0; ks < 2; ++ks)
            aq[qi][ks] = *(const s16x8*)&q_s[base +
                (size_t)(q0 + qi * 16 + L) * DH + ks * 32 + gq * 8];

    f32x4 oacc[2][4];
#pragma unroll
    for (int qi = 0; qi < 2; ++qi)
#pragma unroll
        for (int nd = 0; nd < 4; ++nd) oacc[qi][nd] = (f32x4)0.f;
    float lsum[2] = {0.f, 0.f};

    const int srow = t >> 3;
    const int sc8  = (t & 7) * 8;

    for (int kb = 0; kb < 4; ++kb) {
        __syncthreads();
        {
            const u16* kg = k_s + base + (size_t)(kb * 64 + srow) * DH + sc8;
            gll16(kg, &smem[LDSK + t * 16]);
            const u16* vg = vt_s + base + (size_t)srow * KP + kb * 64 + sc8;
            gll16(vg, &smem[LDSV + t * 16]);
        }
        __syncthreads();

#pragma unroll
        for (int ki = 0; ki < 4; ++ki) {
            const int krow = ki * 16 + L;
            const int kxor = (krow & 7) << 4;
            s16x8 ak0 = *(const s16x8*)&smem[LDSK + krow * 128 + ((gq * 16) ^ kxor)];
            s16x8 ak1 = *(const s16x8*)&smem[LDSK + krow * 128 + ((64 + gq * 16) ^ kxor)];

            f32x4 sacc[2];
            __builtin_amdgcn_s_setprio(1);
#pragma unroll
            for (int qi = 0; qi < 2; ++qi) {
                sacc[qi] = __builtin_amdgcn_mfma_f32_16x16x32_bf16(
                    ak0, aq[qi][0], (f32x4)0.f, 0, 0, 0);
                sacc[qi] = __builtin_amdgcn_mfma_f32_16x16x32_bf16(
                    ak1, aq[qi][1], sacc[qi], 0, 0, 0);
            }
            __builtin_amdgcn_s_setprio(0);

            u32x4 ck4 = *(const u32x4*)&cpk[kb * 64 + ki * 16 + gq * 4];
            int kx[4], ky[4], kz[4];
#pragma unroll
            for (int j = 0; j < 4; ++j) {
                unsigned c = ck4[j];
                kx[j] = (int)(c & 1023u);
                ky[j] = (int)((c >> 10) & 1023u);
                kz[j] = (int)(c >> 20);
            }

            s16x4 pf[2];
#pragma unroll
            for (int qi = 0; qi < 2; ++qi) {
#pragma unroll
                for (int j = 0; j < 4; ++j) {
                    int rx = qx[qi] - kx[j]; rx = rx < -PB ? -PB : (rx > PB ? PB : rx);
                    int ry = qy[qi] - ky[j]; ry = ry < -PB ? -PB : (ry > PB ? PB : ry);
                    int rz = qz[qi] - kz[j]; rz = rz < -PB ? -PB : (rz > PB ? PB : rz);
                    float sv = sacc[qi][j] + rpes[rx + PB]
                             + rpes[RNUM + ry + PB] + rpes[2 * RNUM + rz + PB];
                    float pe = __expf(sv);
                    lsum[qi] += pe;
                    pf[qi][j] = (short)f2b(pe);
                }
            }

            __builtin_amdgcn_s_setprio(1);
#pragma unroll
            for (int nd = 0; nd < 4; ++nd) {
                int d = nd * 16 + L;
                s16x4 vf = *(const s16x4*)&smem[LDSV + d * 128 +
                    (((ki * 16 + gq * 4) * 2) ^ ((d & 7) << 4))];
#pragma unroll
                for (int qi = 0; qi < 2; ++qi)
                    oacc[qi][nd] = __builtin_amdgcn_mfma_f32_16x16x16bf16_1k(
                        pf[qi], vf, oacc[qi][nd], 0, 0, 0);
            }
            __builtin_amdgcn_s_setprio(0);
        }
    }

    float linv[2];
#pragma unroll
    for (int qi = 0; qi < 2; ++qi) {
        float l2 = lsum[qi];
        l2 += __shfl_xor(l2, 16);
        l2 += __shfl_xor(l2, 32);
        linv[qi] = 1.f / l2;
    }

    __syncthreads();
    unsigned* ot = (unsigned*)&smem[wv * 4352];   // [16][68] u32 per wave
#pragma unroll
    for (int qi = 0; qi < 2; ++qi) {
#pragma unroll
        for (int reg = 0; reg < 4; ++reg) {
            float li = __shfl(linv[qi], gq * 4 + reg);
#pragma unroll
            for (int nd = 0; nd < 4; ++nd) {
                float x = oacc[qi][nd][reg] * li;
                u16 hb, lb;
                split1(x, hb, lb);
                ot[(gq * 4 + reg) * 68 + nd * 16 + L] = ((unsigned)hb << 16) | lb;
            }
        }
#pragma unroll
        for (int s = 0; s < 4; ++s) {
            int r = s * 4 + (lane >> 4);
            int c = (lane & 15) * 4;
            u32x4 a = *(const u32x4*)&ot[r * 68 + c];
            int q = q0 + qi * 16 + r;
            unsigned* dst = oa32 + (size_t)(p * KP + q) * CCH + h * DH + c;
            *(u32x4*)dst = a;
        }
    }
}

// ---------------------------------------------------------------------------
// Kernel C: proj GEMM from packed hi|lo A (3-term, fp32-grade).
// BK=64, XCD swizzle, chunk-XOR source-swizzle. Frozen from R15.
// ---------------------------------------------------------------------------
__global__ __launch_bounds__(256, 2) void gemm_proj(
    const unsigned* __restrict__ A32,
    const u16* __restrict__ Bh, const u16* __restrict__ Bl,
    const float* __restrict__ bias, const int* __restrict__ order,
    float* __restrict__ out)
{
    __shared__ __align__(16) unsigned ldsA[128 * 64];      // 32 KB
    __shared__ __align__(16) u16 ldsB[2 * 128 * 64];       // 32 KB
    u16* LBh = ldsB;
    u16* LBl = ldsB + 128 * 64;

    const int t = threadIdx.x;
    const int lane = t & 63, wv = t >> 6;
    const int L = lane & 15, gq = lane >> 4;
    const int wr = wv >> 1, wc = wv & 1;

    const int orig = blockIdx.y * 3 + blockIdx.x;
    const int swz  = (orig & 7) * 192 + (orig >> 3);        // bijective (1536%8==0)
    const int n0 = (swz % 3) * 128;
    const int m0 = (swz / 3) * 128;

    f32x4 acc[4][4];
#pragma unroll
    for (int mi = 0; mi < 4; ++mi)
#pragma unroll
        for (int ni = 0; ni < 4; ++ni) acc[mi][ni] = (f32x4)0.f;

    for (int kc = 0; kc < K1; kc += 64) {
        __syncthreads();
#pragma unroll
        for (int i = 0; i < 8; ++i) {
            int idx = i * 256 + t;
            int r = idx >> 4, j = idx & 15;
            int c4 = (j ^ (r & 15)) * 4;
            gll16(A32 + (size_t)(m0 + r) * K1 + kc + c4, ldsA + idx * 4);
        }
#pragma unroll
        for (int i = 0; i < 4; ++i) {
            int ci = i * 256 + t;
            int r = ci >> 3, j = ci & 7;
            int c8 = (j ^ (r & 7)) * 8;
            size_t gb = (size_t)(n0 + r) * K1 + kc + c8;
            gll16(Bh + gb, LBh + ci * 8);
            gll16(Bl + gb, LBl + ci * 8);
        }
        __syncthreads();
#pragma unroll
        for (int ks = 0; ks < 2; ++ks) {
            s16x8 fah[4], fal[4], fbh[4], fbl[4];
#pragma unroll
            for (int x = 0; x < 4; ++x) {
                int arow = wr * 64 + x * 16 + L;
                int brow = wc * 64 + x * 16 + L;
                int cb = ks * 8 + gq * 2;
                int ca0 = ((cb)     ^ (arow & 15)) * 4;
                int ca1 = ((cb + 1) ^ (arow & 15)) * 4;
                u32x4 a0 = *(const u32x4*)&ldsA[arow * 64 + ca0];
                u32x4 a1 = *(const u32x4*)&ldsA[arow * 64 + ca1];
                union { unsigned w[4]; s16x8 v; } ch, cl;
                ch.w[0] = __builtin_amdgcn_perm(a0[1], a0[0], 0x07060302u);
                ch.w[1] = __builtin_amdgcn_perm(a0[3], a0[2], 0x07060302u);
                ch.w[2] = __builtin_amdgcn_perm(a1[1], a1[0], 0x07060302u);
                ch.w[3] = __builtin_amdgcn_perm(a1[3], a1[2], 0x07060302u);
                cl.w[0] = __builtin_amdgcn_perm(a0[1], a0[0], 0x05040100u);
                cl.w[1] = __builtin_amdgcn_perm(a0[3], a0[2], 0x05040100u);
                cl.w[2] = __builtin_amdgcn_perm(a1[1], a1[0], 0x05040100u);
                cl.w[3] = __builtin_amdgcn_perm(a1[3], a1[2], 0x05040100u);
                fah[x] = ch.v;
                fal[x] = cl.v;
                int kb2 = ((ks * 4 + gq) ^ (brow & 7)) * 8;
                fbh[x] = *(const s16x8*)&LBh[brow * 64 + kb2];
                fbl[x] = *(const s16x8*)&LBl[brow * 64 + kb2];
            }
#pragma unroll
            for (int mi = 0; mi < 4; ++mi)
#pragma unroll
                for (int ni = 0; ni < 4; ++ni) {
                    acc[mi][ni] = __builtin_amdgcn_mfma_f32_16x16x32_bf16(
                        fah[mi], fbh[ni], acc[mi][ni], 0, 0, 0);
                    acc[mi][ni] = __builtin_amdgcn_mfma_f32_16x16x32_bf16(
                        fah[mi], fbl[ni], acc[mi][ni], 0, 0, 0);
                    acc[mi][ni] = __builtin_amdgcn_mfma_f32_16x16x32_bf16(
                        fal[mi], fbh[ni], acc[mi][ni], 0, 0, 0);
                }
        }
    }

    float bfrag[4];
#pragma unroll
    for (int ni = 0; ni < 4; ++ni) bfrag[ni] = bias[n0 + wc * 64 + ni * 16 + L];

    __syncthreads();
    float* otp = (float*)ldsA + wv * 1088;   // [16][68] f32 per wave
#pragma unroll
    for (int mi = 0; mi < 4; ++mi) {
#pragma unroll
        for (int reg = 0; reg < 4; ++reg)
#pragma unroll
            for (int ni = 0; ni < 4; ++ni)
                otp[(gq * 4 + reg) * 68 + ni * 16 + L] = acc[mi][ni][reg] + bfrag[ni];
#pragma unroll
        for (int s = 0; s < 4; ++s) {
            int r = s * 4 + (lane >> 4);
            int c = (lane & 15) * 4;
            f32x4 a = *(const f32x4*)&otp[r * 68 + c];
            int j = m0 + wr * 64 + mi * 16 + r;
            float* dst = out + (size_t)order[j] * CCH + n0 + wc * 64 + c;
            *(f32x4*)dst = a;
        }
    }
}

// ---------------------------------------------------------------------------
extern "C" void kernel_launch(void* const* d_in, const int* in_sizes, int n_in,
                              void* d_out, int out_size, void* d_ws, size_t ws_size,
                              hipStream_t stream) {
    const float* feat      = (const float*)d_in[0];
    const float* qkv_w     = (const float*)d_in[1];
    const float* qkv_b     = (const float*)d_in[2];
    const float* proj_w    = (const float*)d_in[3];
    const float* proj_b    = (const float*)d_in[4];
    const float* rpe_table = (const float*)d_in[5];
    const int*   order     = (const int*)d_in[6];
    const int*   gcoord    = (const int*)d_in[8];
    float* out = (float*)d_out;

    const size_t NC = (size_t)NPTS * CCH;
    u16* fh   = (u16*)d_ws;
    u16* qwh  = fh + NC;
    u16* qwl  = qwh + (size_t)1152 * 384;
    u16* pwh  = qwl + (size_t)1152 * 384;
    u16* pwl  = pwh + (size_t)384 * 384;
    u16* qs   = pwl + (size_t)384 * 384;
    u16* ks   = qs + NC;
    u16* vts  = ks + NC;
    unsigned* oa32  = (unsigned*)(vts + NC);
    unsigned* cpk_g = oa32 + NC;

    split_arr<<<(1152 * 384 / 4 + 255) / 256, 256, 0, stream>>>(qkv_w, qwh, qwl, 1152 * 384 / 4);
    split_arr<<<(384 * 384 / 4 + 255) / 256, 256, 0, stream>>>(proj_w, pwh, pwl, 384 * 384 / 4);
    gather_h<<<NPTS * 96 / 256, 256, 0, stream>>>(feat, order, fh);
    pack_coords<<<NPTS / 256, 256, 0, stream>>>(order, gcoord, cpk_g);

    gemm_qkv<<<dim3(9, NPTS / 128), 256, 0, stream>>>(
        fh, qwh, qwl, qkv_b, qs, ks, vts);
    attn_mfma<<<dim3(NPATCH, NH), 512, 0, stream>>>(
        qs, ks, vts, cpk_g, rpe_table, oa32);
    gemm_proj<<<dim3(3, NPTS / 128), 256, 0, stream>>>(
        oa32, pwh, pwl, proj_b, order, out);
}

// Round 18
// 299.233 us; speedup vs baseline: 1.3784x; 1.3784x over previous
//
#include <hip/hip_runtime.h>
#include <hip/hip_bf16.h>

// Problem constants
#define NPTS   65536
#define CCH    384
#define NH     6
#define DH     64
#define KP     256   // patch size
#define NPATCH 256   // NPTS / KP
#define PB     20    // POS_BND
#define RNUM   41    // 2*PB+1
#define K1     384   // GEMM inner dim

typedef float f32x4 __attribute__((ext_vector_type(4)));
typedef short s16x8 __attribute__((ext_vector_type(8)));
typedef short s16x4 __attribute__((ext_vector_type(4)));
typedef unsigned u32x4 __attribute__((ext_vector_type(4)));
typedef unsigned short u16;
typedef u16 u16x4 __attribute__((ext_vector_type(4)));

static __device__ __forceinline__ u16 f2b(float f) {
    union { __hip_bfloat16 h; u16 u; } cv;
    cv.h = __float2bfloat16(f);
    return cv.u;
}
static __device__ __forceinline__ float b2f(u16 u) {
    union { float f; unsigned v; } cv; cv.v = ((unsigned)u) << 16; return cv.f;
}
static __device__ __forceinline__ void split1(float x, u16& h, u16& l) {
    h = f2b(x);
    l = f2b(x - b2f(h));
}

typedef __attribute__((address_space(3))) unsigned lds_u;
typedef const __attribute__((address_space(1))) unsigned glob_u;
static __device__ __forceinline__ void gll16(const void* g, void* l) {
    __builtin_amdgcn_global_load_lds((glob_u*)g, (lds_u*)l, 16, 0, 0);
}

// ---------------------------------------------------------------------------
// Prep kernels
// ---------------------------------------------------------------------------
__global__ __launch_bounds__(256) void split_arr(
    const float* __restrict__ s, u16* __restrict__ h, u16* __restrict__ l, int n4)
{
    int i = blockIdx.x * 256 + threadIdx.x;
    if (i >= n4) return;
    float4 v = ((const float4*)s)[i];
    u16 h0, l0, h1, l1, h2, l2, h3, l3;
    split1(v.x, h0, l0); split1(v.y, h1, l1);
    split1(v.z, h2, l2); split1(v.w, h3, l3);
    u16x4 hv, lv;
    hv[0] = h0; hv[1] = h1; hv[2] = h2; hv[3] = h3;
    lv[0] = l0; lv[1] = l1; lv[2] = l2; lv[3] = l3;
    *(u16x4*)&h[(size_t)i * 4] = hv;
    *(u16x4*)&l[(size_t)i * 4] = lv;
}

// Gather fh = bf16(feat[order[j]]) only
__global__ __launch_bounds__(256) void gather_h(
    const float* __restrict__ feat, const int* __restrict__ order,
    u16* __restrict__ fh)
{
    int i = blockIdx.x * 256 + threadIdx.x;   // over NPTS*96 float4s
    int r = i / 96, c4 = i % 96;
    int o = order[r];
    float4 v = *((const float4*)(feat + (size_t)o * CCH) + c4);
    u16x4 hv;
    hv[0] = f2b(v.x); hv[1] = f2b(v.y); hv[2] = f2b(v.z); hv[3] = f2b(v.w);
    *(u16x4*)&fh[(size_t)r * CCH + c4 * 4] = hv;
}

__global__ __launch_bounds__(256) void pack_coords(
    const int* __restrict__ order, const int* __restrict__ gcoord,
    unsigned* __restrict__ cpk_g)
{
    int j = blockIdx.x * 256 + threadIdx.x;
    int o = order[j];
    const int* gc = gcoord + (size_t)o * 3;
    cpk_g[j] = (unsigned)gc[0] | ((unsigned)gc[1] << 10) | ((unsigned)gc[2] << 20);
}

// ---------------------------------------------------------------------------
// Kernel A: 2-term split GEMM (qkv): C = Ah*Bh + Ah*Bl
// BK=64 (48 KB LDS, (256,3)), XCD-bijective swizzle, chunk-XOR source-swizzle
// (staging source chunk j^=(r&7), LDS linear; read chunk (ks*4+gq)^(row&7)).
// R16-verified: 112 us, MfmaUtil 46.5%, bank conflicts 0.
// ---------------------------------------------------------------------------
__global__ __launch_bounds__(256, 3) void gemm_qkv(
    const u16* __restrict__ Ah,
    const u16* __restrict__ Bh, const u16* __restrict__ Bl,
    const float* __restrict__ bias,
    u16* __restrict__ q_out, u16* __restrict__ k_out, u16* __restrict__ vt_out)
{
    __shared__ __align__(16) u16 lds[3 * 128 * 64];   // 48 KB
    u16* LAh = lds;
    u16* LBh = lds + 128 * 64;
    u16* LBl = lds + 2 * 128 * 64;

    const int t = threadIdx.x;
    const int lane = t & 63, wv = t >> 6;
    const int L = lane & 15, gq = lane >> 4;
    const int wr = wv >> 1, wc = wv & 1;

    const int orig = blockIdx.y * 9 + blockIdx.x;          // linear, x fastest
    const int swz  = (orig & 7) * 576 + (orig >> 3);        // bijective (4608%8==0)
    const int n0 = (swz % 9) * 128;
    const int m0 = (swz / 9) * 128;

    f32x4 acc[4][4];
#pragma unroll
    for (int mi = 0; mi < 4; ++mi)
#pragma unroll
        for (int ni = 0; ni < 4; ++ni) acc[mi][ni] = (f32x4)0.f;

    for (int kc = 0; kc < K1; kc += 64) {
        __syncthreads();
#pragma unroll
        for (int i = 0; i < 4; ++i) {
            int ci = i * 256 + t;                 // 0..1023
            int r = ci >> 3, j = ci & 7;          // row, chunk
            int c8 = (j ^ (r & 7)) * 8;           // source chunk permuted
            size_t ga = (size_t)(m0 + r) * K1 + kc + c8;
            size_t gb = (size_t)(n0 + r) * K1 + kc + c8;
            gll16(Ah + ga, LAh + ci * 8);
            gll16(Bh + gb, LBh + ci * 8);
            gll16(Bl + gb, LBl + ci * 8);
        }
        __syncthreads();
#pragma unroll
        for (int ks = 0; ks < 2; ++ks) {
            s16x8 fah[4], fbh[4], fbl[4];
#pragma unroll
            for (int x = 0; x < 4; ++x) {
                int arow = wr * 64 + x * 16 + L;
                int brow = wc * 64 + x * 16 + L;
                int ka  = ((ks * 4 + gq) ^ (arow & 7)) * 8;
                int kb2 = ((ks * 4 + gq) ^ (brow & 7)) * 8;
                fah[x] = *(const s16x8*)&LAh[arow * 64 + ka];
                fbh[x] = *(const s16x8*)&LBh[brow * 64 + kb2];
                fbl[x] = *(const s16x8*)&LBl[brow * 64 + kb2];
            }
#pragma unroll
            for (int mi = 0; mi < 4; ++mi)
#pragma unroll
                for (int ni = 0; ni < 4; ++ni) {
                    acc[mi][ni] = __builtin_amdgcn_mfma_f32_16x16x32_bf16(
                        fah[mi], fbh[ni], acc[mi][ni], 0, 0, 0);
                    acc[mi][ni] = __builtin_amdgcn_mfma_f32_16x16x32_bf16(
                        fah[mi], fbl[ni], acc[mi][ni], 0, 0, 0);
                }
        }
    }

    float bfrag[4];
#pragma unroll
    for (int ni = 0; ni < 4; ++ni) bfrag[ni] = bias[n0 + wc * 64 + ni * 16 + L];

    const int cq   = n0 + wc * 64;
    const int ssel = cq / CCH;
    const int hh   = (cq % CCH) / DH;

    if (ssel == 2) {
#pragma unroll
        for (int mi = 0; mi < 4; ++mi) {
            int jb = m0 + wr * 64 + mi * 16;
            int p = jb >> 8, kr0 = (jb & 255) + gq * 4;
            size_t hb = (size_t)(p * NH + hh) * DH;
#pragma unroll
            for (int ni = 0; ni < 4; ++ni) {
                int d = ni * 16 + L;
                u16x4 w;
#pragma unroll
                for (int reg = 0; reg < 4; ++reg)
                    w[reg] = f2b(acc[mi][ni][reg] + bfrag[ni]);
                int kswz = (kr0 & ~63) + ((kr0 & 63) ^ ((d & 7) << 3));
                *(u16x4*)&vt_out[(hb + d) * KP + kswz] = w;
            }
        }
    } else if (ssel == 1) {
#pragma unroll
        for (int mi = 0; mi < 4; ++mi)
#pragma unroll
            for (int reg = 0; reg < 4; ++reg) {
                int j = m0 + wr * 64 + mi * 16 + gq * 4 + reg;
                int kk = j & 255;
                u16* orow = k_out + ((size_t)((j >> 8) * NH + hh) * KP + kk) * DH;
                int sw = (kk & 7) << 3;
#pragma unroll
                for (int ni = 0; ni < 4; ++ni)
                    orow[(ni * 16 + L) ^ sw] = f2b(acc[mi][ni][reg] + bfrag[ni]);
            }
    } else {
#pragma unroll
        for (int mi = 0; mi < 4; ++mi)
#pragma unroll
            for (int reg = 0; reg < 4; ++reg) {
                int j = m0 + wr * 64 + mi * 16 + gq * 4 + reg;
                u16* orow = q_out + ((size_t)((j >> 8) * NH + hh) * KP + (j & 255)) * DH;
#pragma unroll
                for (int ni = 0; ni < 4; ++ni)
                    orow[ni * 16 + L] = f2b((acc[mi][ni][reg] + bfrag[ni]) * 0.125f);
            }
    }
}

// ---------------------------------------------------------------------------
// Kernel B: swapped-operand MFMA flash attention per (patch, head).
// 8 waves x 32 q-rows (512 threads). Frozen from R12.
// ---------------------------------------------------------------------------
#define LDSK 0
#define LDSV 8192
#define CPKO 16384
#define RPEO 17408
#define SMEMSZ 35328          // epilogue: 8 waves x 4352B transpose buffers

__global__ __launch_bounds__(512, 4) void attn_mfma(
    const u16* __restrict__ q_s, const u16* __restrict__ k_s,
    const u16* __restrict__ vt_s, const unsigned* __restrict__ cpk_g,
    const float* __restrict__ rpe_table, unsigned* __restrict__ oa32)
{
    __shared__ __align__(16) unsigned char smem[SMEMSZ];
    unsigned* cpk  = (unsigned*)&smem[CPKO];
    float*    rpes = (float*)&smem[RPEO];

    const int t    = threadIdx.x;
    const int p    = blockIdx.x, h = blockIdx.y;
    const int lane = t & 63, wv = t >> 6;
    const int L    = lane & 15, gq = lane >> 4;
    const int q0   = wv * 32;
    const size_t base = (size_t)(p * NH + h) * KP * DH;

    if (t < KP) cpk[t] = cpk_g[p * KP + t];
    if (t >= KP && t < KP + 3 * RNUM) rpes[t - KP] = rpe_table[(t - KP) * NH + h];
    __syncthreads();

    int qx[2], qy[2], qz[2];
#pragma unroll
    for (int qi = 0; qi < 2; ++qi) {
        unsigned c = cpk[q0 + qi * 16 + L];
        qx[qi] = (int)(c & 1023u);
        qy[qi] = (int)((c >> 10) & 1023u);
        qz[qi] = (int)(c >> 20);
    }

    s16x8 aq[2][2];
#pragma unroll
    for (int qi = 0; qi < 2; ++qi)
#pragma unroll
        for (int ks = 0; ks < 2; ++ks)
            aq[qi][ks] = *(const s16x8*)&q_s[base +
                (size_t)(q0 + qi * 16 + L) * DH + ks * 32 + gq * 8];

    f32x4 oacc[2][4];
#pragma unroll
    for (int qi = 0; qi < 2; ++qi)
#pragma unroll
        for (int nd = 0; nd < 4; ++nd) oacc[qi][nd] = (f32x4)0.f;
    float lsum[2] = {0.f, 0.f};

    const int srow = t >> 3;
    const int sc8  = (t & 7) * 8;

    for (int kb = 0; kb < 4; ++kb) {
        __syncthreads();
        {
            const u16* kg = k_s + base + (size_t)(kb * 64 + srow) * DH + sc8;
            gll16(kg, &smem[LDSK + t * 16]);
            const u16* vg = vt_s + base + (size_t)srow * KP + kb * 64 + sc8;
            gll16(vg, &smem[LDSV + t * 16]);
        }
        __syncthreads();

#pragma unroll
        for (int ki = 0; ki < 4; ++ki) {
            const int krow = ki * 16 + L;
            const int kxor = (krow & 7) << 4;
            s16x8 ak0 = *(const s16x8*)&smem[LDSK + krow * 128 + ((gq * 16) ^ kxor)];
            s16x8 ak1 = *(const s16x8*)&smem[LDSK + krow * 128 + ((64 + gq * 16) ^ kxor)];

            f32x4 sacc[2];
            __builtin_amdgcn_s_setprio(1);
#pragma unroll
            for (int qi = 0; qi < 2; ++qi) {
                sacc[qi] = __builtin_amdgcn_mfma_f32_16x16x32_bf16(
                    ak0, aq[qi][0], (f32x4)0.f, 0, 0, 0);
                sacc[qi] = __builtin_amdgcn_mfma_f32_16x16x32_bf16(
                    ak1, aq[qi][1], sacc[qi], 0, 0, 0);
            }
            __builtin_amdgcn_s_setprio(0);

            u32x4 ck4 = *(const u32x4*)&cpk[kb * 64 + ki * 16 + gq * 4];
            int kx[4], ky[4], kz[4];
#pragma unroll
            for (int j = 0; j < 4; ++j) {
                unsigned c = ck4[j];
                kx[j] = (int)(c & 1023u);
                ky[j] = (int)((c >> 10) & 1023u);
                kz[j] = (int)(c >> 20);
            }

            s16x4 pf[2];
#pragma unroll
            for (int qi = 0; qi < 2; ++qi) {
#pragma unroll
                for (int j = 0; j < 4; ++j) {
                    int rx = qx[qi] - kx[j]; rx = rx < -PB ? -PB : (rx > PB ? PB : rx);
                    int ry = qy[qi] - ky[j]; ry = ry < -PB ? -PB : (ry > PB ? PB : ry);
                    int rz = qz[qi] - kz[j]; rz = rz < -PB ? -PB : (rz > PB ? PB : rz);
                    float sv = sacc[qi][j] + rpes[rx + PB]
                             + rpes[RNUM + ry + PB] + rpes[2 * RNUM + rz + PB];
                    float pe = __expf(sv);
                    lsum[qi] += pe;
                    pf[qi][j] = (short)f2b(pe);
                }
            }

            __builtin_amdgcn_s_setprio(1);
#pragma unroll
            for (int nd = 0; nd < 4; ++nd) {
                int d = nd * 16 + L;
                s16x4 vf = *(const s16x4*)&smem[LDSV + d * 128 +
                    (((ki * 16 + gq * 4) * 2) ^ ((d & 7) << 4))];
#pragma unroll
                for (int qi = 0; qi < 2; ++qi)
                    oacc[qi][nd] = __builtin_amdgcn_mfma_f32_16x16x16bf16_1k(
                        pf[qi], vf, oacc[qi][nd], 0, 0, 0);
            }
            __builtin_amdgcn_s_setprio(0);
        }
    }

    float linv[2];
#pragma unroll
    for (int qi = 0; qi < 2; ++qi) {
        float l2 = lsum[qi];
        l2 += __shfl_xor(l2, 16);
        l2 += __shfl_xor(l2, 32);
        linv[qi] = 1.f / l2;
    }

    __syncthreads();
    unsigned* ot = (unsigned*)&smem[wv * 4352];   // [16][68] u32 per wave
#pragma unroll
    for (int qi = 0; qi < 2; ++qi) {
#pragma unroll
        for (int reg = 0; reg < 4; ++reg) {
            float li = __shfl(linv[qi], gq * 4 + reg);
#pragma unroll
            for (int nd = 0; nd < 4; ++nd) {
                float x = oacc[qi][nd][reg] * li;
                u16 hb, lb;
                split1(x, hb, lb);
                ot[(gq * 4 + reg) * 68 + nd * 16 + L] = ((unsigned)hb << 16) | lb;
            }
        }
#pragma unroll
        for (int s = 0; s < 4; ++s) {
            int r = s * 4 + (lane >> 4);
            int c = (lane & 15) * 4;
            u32x4 a = *(const u32x4*)&ot[r * 68 + c];
            int q = q0 + qi * 16 + r;
            unsigned* dst = oa32 + (size_t)(p * KP + q) * CCH + h * DH + c;
            *(u32x4*)dst = a;
        }
    }
}

// ---------------------------------------------------------------------------
// Kernel C: proj GEMM from packed hi|lo A (3-term, fp32-grade).
// BK=64, XCD swizzle, chunk-XOR source-swizzle. Frozen from R15/R16.
// ---------------------------------------------------------------------------
__global__ __launch_bounds__(256, 2) void gemm_proj(
    const unsigned* __restrict__ A32,
    const u16* __restrict__ Bh, const u16* __restrict__ Bl,
    const float* __restrict__ bias, const int* __restrict__ order,
    float* __restrict__ out)
{
    __shared__ __align__(16) unsigned ldsA[128 * 64];      // 32 KB
    __shared__ __align__(16) u16 ldsB[2 * 128 * 64];       // 32 KB
    u16* LBh = ldsB;
    u16* LBl = ldsB + 128 * 64;

    const int t = threadIdx.x;
    const int lane = t & 63, wv = t >> 6;
    const int L = lane & 15, gq = lane >> 4;
    const int wr = wv >> 1, wc = wv & 1;

    const int orig = blockIdx.y * 3 + blockIdx.x;
    const int swz  = (orig & 7) * 192 + (orig >> 3);        // bijective (1536%8==0)
    const int n0 = (swz % 3) * 128;
    const int m0 = (swz / 3) * 128;

    f32x4 acc[4][4];
#pragma unroll
    for (int mi = 0; mi < 4; ++mi)
#pragma unroll
        for (int ni = 0; ni < 4; ++ni) acc[mi][ni] = (f32x4)0.f;

    for (int kc = 0; kc < K1; kc += 64) {
        __syncthreads();
        // A: 128 rows x 16 chunks (16B) = 2048; source chunk ^(r&15)
#pragma unroll
        for (int i = 0; i < 8; ++i) {
            int idx = i * 256 + t;
            int r = idx >> 4, j = idx & 15;
            int c4 = (j ^ (r & 15)) * 4;
            gll16(A32 + (size_t)(m0 + r) * K1 + kc + c4, ldsA + idx * 4);
        }
        // B: 128 rows x 8 chunks = 1024 each; source chunk ^(r&7)
#pragma unroll
        for (int i = 0; i < 4; ++i) {
            int ci = i * 256 + t;
            int r = ci >> 3, j = ci & 7;
            int c8 = (j ^ (r & 7)) * 8;
            size_t gb = (size_t)(n0 + r) * K1 + kc + c8;
            gll16(Bh + gb, LBh + ci * 8);
            gll16(Bl + gb, LBl + ci * 8);
        }
        __syncthreads();
#pragma unroll
        for (int ks = 0; ks < 2; ++ks) {
            s16x8 fah[4], fal[4], fbh[4], fbl[4];
#pragma unroll
            for (int x = 0; x < 4; ++x) {
                int arow = wr * 64 + x * 16 + L;
                int brow = wc * 64 + x * 16 + L;
                int cb = ks * 8 + gq * 2;
                int ca0 = ((cb)     ^ (arow & 15)) * 4;
                int ca1 = ((cb + 1) ^ (arow & 15)) * 4;
                u32x4 a0 = *(const u32x4*)&ldsA[arow * 64 + ca0];
                u32x4 a1 = *(const u32x4*)&ldsA[arow * 64 + ca1];
                union { unsigned w[4]; s16x8 v; } ch, cl;
                ch.w[0] = __builtin_amdgcn_perm(a0[1], a0[0], 0x07060302u);
                ch.w[1] = __builtin_amdgcn_perm(a0[3], a0[2], 0x07060302u);
                ch.w[2] = __builtin_amdgcn_perm(a1[1], a1[0], 0x07060302u);
                ch.w[3] = __builtin_amdgcn_perm(a1[3], a1[2], 0x07060302u);
                cl.w[0] = __builtin_amdgcn_perm(a0[1], a0[0], 0x05040100u);
                cl.w[1] = __builtin_amdgcn_perm(a0[3], a0[2], 0x05040100u);
                cl.w[2] = __builtin_amdgcn_perm(a1[1], a1[0], 0x05040100u);
                cl.w[3] = __builtin_amdgcn_perm(a1[3], a1[2], 0x05040100u);
                fah[x] = ch.v;
                fal[x] = cl.v;
                int kb2 = ((ks * 4 + gq) ^ (brow & 7)) * 8;
                fbh[x] = *(const s16x8*)&LBh[brow * 64 + kb2];
                fbl[x] = *(const s16x8*)&LBl[brow * 64 + kb2];
            }
#pragma unroll
            for (int mi = 0; mi < 4; ++mi)
#pragma unroll
                for (int ni = 0; ni < 4; ++ni) {
                    acc[mi][ni] = __builtin_amdgcn_mfma_f32_16x16x32_bf16(
                        fah[mi], fbh[ni], acc[mi][ni], 0, 0, 0);
                    acc[mi][ni] = __builtin_amdgcn_mfma_f32_16x16x32_bf16(
                        fah[mi], fbl[ni], acc[mi][ni], 0, 0, 0);
                    acc[mi][ni] = __builtin_amdgcn_mfma_f32_16x16x32_bf16(
                        fal[mi], fbh[ni], acc[mi][ni], 0, 0, 0);
                }
        }
    }

    float bfrag[4];
#pragma unroll
    for (int ni = 0; ni < 4; ++ni) bfrag[ni] = bias[n0 + wc * 64 + ni * 16 + L];

    __syncthreads();
    float* otp = (float*)ldsA + wv * 1088;   // [16][68] f32 per wave
#pragma unroll
    for (int mi = 0; mi < 4; ++mi) {
#pragma unroll
        for (int reg = 0; reg < 4; ++reg)
#pragma unroll
            for (int ni = 0; ni < 4; ++ni)
                otp[(gq * 4 + reg) * 68 + ni * 16 + L] = acc[mi][ni][reg] + bfrag[ni];
#pragma unroll
        for (int s = 0; s < 4; ++s) {
            int r = s * 4 + (lane >> 4);
            int c = (lane & 15) * 4;
            f32x4 a = *(const f32x4*)&otp[r * 68 + c];
            int j = m0 + wr * 64 + mi * 16 + r;
            float* dst = out + (size_t)order[j] * CCH + n0 + wc * 64 + c;
            *(f32x4*)dst = a;
        }
    }
}

// ---------------------------------------------------------------------------
extern "C" void kernel_launch(void* const* d_in, const int* in_sizes, int n_in,
                              void* d_out, int out_size, void* d_ws, size_t ws_size,
                              hipStream_t stream) {
    const float* feat      = (const float*)d_in[0];
    const float* qkv_w     = (const float*)d_in[1];
    const float* qkv_b     = (const float*)d_in[2];
    const float* proj_w    = (const float*)d_in[3];
    const float* proj_b    = (const float*)d_in[4];
    const float* rpe_table = (const float*)d_in[5];
    const int*   order     = (const int*)d_in[6];
    const int*   gcoord    = (const int*)d_in[8];
    float* out = (float*)d_out;

    const size_t NC = (size_t)NPTS * CCH;
    u16* fh   = (u16*)d_ws;
    u16* qwh  = fh + NC;
    u16* qwl  = qwh + (size_t)1152 * 384;
    u16* pwh  = qwl + (size_t)1152 * 384;
    u16* pwl  = pwh + (size_t)384 * 384;
    u16* qs   = pwl + (size_t)384 * 384;
    u16* ks   = qs + NC;
    u16* vts  = ks + NC;
    unsigned* oa32  = (unsigned*)(vts + NC);
    unsigned* cpk_g = oa32 + NC;

    split_arr<<<(1152 * 384 / 4 + 255) / 256, 256, 0, stream>>>(qkv_w, qwh, qwl, 1152 * 384 / 4);
    split_arr<<<(384 * 384 / 4 + 255) / 256, 256, 0, stream>>>(proj_w, pwh, pwl, 384 * 384 / 4);
    gather_h<<<NPTS * 96 / 256, 256, 0, stream>>>(feat, order, fh);
    pack_coords<<<NPTS / 256, 256, 0, stream>>>(order, gcoord, cpk_g);

    gemm_qkv<<<dim3(9, NPTS / 128), 256, 0, stream>>>(
        fh, qwh, qwl, qkv_b, qs, ks, vts);
    attn_mfma<<<dim3(NPATCH, NH), 512, 0, stream>>>(
        qs, ks, vts, cpk_g, rpe_table, oa32);
    gemm_proj<<<dim3(3, NPTS / 128), 256, 0, stream>>>(
        oa32, pwh, pwl, proj_b, order, out);
}

// Round 19
// 238.313 us; speedup vs baseline: 1.7308x; 1.2556x over previous
//
#include <hip/hip_runtime.h>
#include <hip/hip_bf16.h>

// Problem constants
#define NPTS   65536
#define CCH    384
#define NH     6
#define DH     64
#define KP     256   // patch size
#define NPATCH 256   // NPTS / KP
#define PB     20    // POS_BND
#define RNUM   41    // 2*PB+1
#define K1     384   // GEMM inner dim

typedef float f32x4 __attribute__((ext_vector_type(4)));
typedef short s16x8 __attribute__((ext_vector_type(8)));
typedef short s16x4 __attribute__((ext_vector_type(4)));
typedef unsigned u32x4 __attribute__((ext_vector_type(4)));
typedef unsigned short u16;
typedef u16 u16x4 __attribute__((ext_vector_type(4)));

static __device__ __forceinline__ u16 f2b(float f) {
    union { __hip_bfloat16 h; u16 u; } cv;
    cv.h = __float2bfloat16(f);
    return cv.u;
}
static __device__ __forceinline__ float b2f(u16 u) {
    union { float f; unsigned v; } cv; cv.v = ((unsigned)u) << 16; return cv.f;
}
static __device__ __forceinline__ void split1(float x, u16& h, u16& l) {
    h = f2b(x);
    l = f2b(x - b2f(h));
}

typedef __attribute__((address_space(3))) unsigned lds_u;
typedef const __attribute__((address_space(1))) unsigned glob_u;
static __device__ __forceinline__ void gll16(const void* g, void* l) {
    __builtin_amdgcn_global_load_lds((glob_u*)g, (lds_u*)l, 16, 0, 0);
}

// ---------------------------------------------------------------------------
// Prep kernels
// ---------------------------------------------------------------------------
__global__ __launch_bounds__(256) void split_arr(
    const float* __restrict__ s, u16* __restrict__ h, u16* __restrict__ l, int n4)
{
    int i = blockIdx.x * 256 + threadIdx.x;
    if (i >= n4) return;
    float4 v = ((const float4*)s)[i];
    u16 h0, l0, h1, l1, h2, l2, h3, l3;
    split1(v.x, h0, l0); split1(v.y, h1, l1);
    split1(v.z, h2, l2); split1(v.w, h3, l3);
    u16x4 hv, lv;
    hv[0] = h0; hv[1] = h1; hv[2] = h2; hv[3] = h3;
    lv[0] = l0; lv[1] = l1; lv[2] = l2; lv[3] = l3;
    *(u16x4*)&h[(size_t)i * 4] = hv;
    *(u16x4*)&l[(size_t)i * 4] = lv;
}

__global__ __launch_bounds__(256) void cast_bf16(
    const float* __restrict__ s, u16* __restrict__ d, int n4)
{
    int i = blockIdx.x * 256 + threadIdx.x;
    if (i >= n4) return;
    float4 v = ((const float4*)s)[i];
    u16x4 hv;
    hv[0] = f2b(v.x); hv[1] = f2b(v.y); hv[2] = f2b(v.z); hv[3] = f2b(v.w);
    *(u16x4*)&d[(size_t)i * 4] = hv;
}

// Gather fh = bf16(feat[order[j]])
__global__ __launch_bounds__(256) void gather_h(
    const float* __restrict__ feat, const int* __restrict__ order,
    u16* __restrict__ fh)
{
    int i = blockIdx.x * 256 + threadIdx.x;   // over NPTS*96 float4s
    int r = i / 96, c4 = i % 96;
    int o = order[r];
    float4 v = *((const float4*)(feat + (size_t)o * CCH) + c4);
    u16x4 hv;
    hv[0] = f2b(v.x); hv[1] = f2b(v.y); hv[2] = f2b(v.z); hv[3] = f2b(v.w);
    *(u16x4*)&fh[(size_t)r * CCH + c4 * 4] = hv;
}

__global__ __launch_bounds__(256) void pack_coords(
    const int* __restrict__ order, const int* __restrict__ gcoord,
    unsigned* __restrict__ cpk_g)
{
    int j = blockIdx.x * 256 + threadIdx.x;
    int o = order[j];
    const int* gc = gcoord + (size_t)o * 3;
    cpk_g[j] = (unsigned)gc[0] | ((unsigned)gc[1] << 10) | ((unsigned)gc[2] << 20);
}

// ---------------------------------------------------------------------------
// Kernel A: 1-term bf16 GEMM (qkv): C = Ah*Bh
// BK=64, 32 KB LDS -> (256,4) = 4 blocks/CU. XCD-bijective swizzle,
// chunk-XOR source-swizzle (conflict-free, R16-verified pattern).
// ---------------------------------------------------------------------------
__global__ __launch_bounds__(256, 4) void gemm_qkv(
    const u16* __restrict__ Ah, const u16* __restrict__ Bh,
    const float* __restrict__ bias,
    u16* __restrict__ q_out, u16* __restrict__ k_out, u16* __restrict__ vt_out)
{
    __shared__ __align__(16) u16 lds[2 * 128 * 64];   // 32 KB
    u16* LAh = lds;
    u16* LBh = lds + 128 * 64;

    const int t = threadIdx.x;
    const int lane = t & 63, wv = t >> 6;
    const int L = lane & 15, gq = lane >> 4;
    const int wr = wv >> 1, wc = wv & 1;

    const int orig = blockIdx.y * 9 + blockIdx.x;          // linear, x fastest
    const int swz  = (orig & 7) * 576 + (orig >> 3);        // bijective (4608%8==0)
    const int n0 = (swz % 9) * 128;
    const int m0 = (swz / 9) * 128;

    f32x4 acc[4][4];
#pragma unroll
    for (int mi = 0; mi < 4; ++mi)
#pragma unroll
        for (int ni = 0; ni < 4; ++ni) acc[mi][ni] = (f32x4)0.f;

    for (int kc = 0; kc < K1; kc += 64) {
        __syncthreads();
#pragma unroll
        for (int i = 0; i < 4; ++i) {
            int ci = i * 256 + t;                 // 0..1023
            int r = ci >> 3, j = ci & 7;          // row, chunk
            int c8 = (j ^ (r & 7)) * 8;           // source chunk permuted
            gll16(Ah + (size_t)(m0 + r) * K1 + kc + c8, LAh + ci * 8);
            gll16(Bh + (size_t)(n0 + r) * K1 + kc + c8, LBh + ci * 8);
        }
        __syncthreads();
#pragma unroll
        for (int ks = 0; ks < 2; ++ks) {
            s16x8 fah[4], fbh[4];
#pragma unroll
            for (int x = 0; x < 4; ++x) {
                int arow = wr * 64 + x * 16 + L;
                int brow = wc * 64 + x * 16 + L;
                int ka  = ((ks * 4 + gq) ^ (arow & 7)) * 8;
                int kb2 = ((ks * 4 + gq) ^ (brow & 7)) * 8;
                fah[x] = *(const s16x8*)&LAh[arow * 64 + ka];
                fbh[x] = *(const s16x8*)&LBh[brow * 64 + kb2];
            }
#pragma unroll
            for (int mi = 0; mi < 4; ++mi)
#pragma unroll
                for (int ni = 0; ni < 4; ++ni)
                    acc[mi][ni] = __builtin_amdgcn_mfma_f32_16x16x32_bf16(
                        fah[mi], fbh[ni], acc[mi][ni], 0, 0, 0);
        }
    }

    float bfrag[4];
#pragma unroll
    for (int ni = 0; ni < 4; ++ni) bfrag[ni] = bias[n0 + wc * 64 + ni * 16 + L];

    const int cq   = n0 + wc * 64;
    const int ssel = cq / CCH;
    const int hh   = (cq % CCH) / DH;

    if (ssel == 2) {
#pragma unroll
        for (int mi = 0; mi < 4; ++mi) {
            int jb = m0 + wr * 64 + mi * 16;
            int p = jb >> 8, kr0 = (jb & 255) + gq * 4;
            size_t hb = (size_t)(p * NH + hh) * DH;
#pragma unroll
            for (int ni = 0; ni < 4; ++ni) {
                int d = ni * 16 + L;
                u16x4 w;
#pragma unroll
                for (int reg = 0; reg < 4; ++reg)
                    w[reg] = f2b(acc[mi][ni][reg] + bfrag[ni]);
                int kswz = (kr0 & ~63) + ((kr0 & 63) ^ ((d & 7) << 3));
                *(u16x4*)&vt_out[(hb + d) * KP + kswz] = w;
            }
        }
    } else if (ssel == 1) {
#pragma unroll
        for (int mi = 0; mi < 4; ++mi)
#pragma unroll
            for (int reg = 0; reg < 4; ++reg) {
                int j = m0 + wr * 64 + mi * 16 + gq * 4 + reg;
                int kk = j & 255;
                u16* orow = k_out + ((size_t)((j >> 8) * NH + hh) * KP + kk) * DH;
                int sw = (kk & 7) << 3;
#pragma unroll
                for (int ni = 0; ni < 4; ++ni)
                    orow[(ni * 16 + L) ^ sw] = f2b(acc[mi][ni][reg] + bfrag[ni]);
            }
    } else {
#pragma unroll
        for (int mi = 0; mi < 4; ++mi)
#pragma unroll
            for (int reg = 0; reg < 4; ++reg) {
                int j = m0 + wr * 64 + mi * 16 + gq * 4 + reg;
                u16* orow = q_out + ((size_t)((j >> 8) * NH + hh) * KP + (j & 255)) * DH;
#pragma unroll
                for (int ni = 0; ni < 4; ++ni)
                    orow[ni * 16 + L] = f2b((acc[mi][ni][reg] + bfrag[ni]) * 0.125f);
            }
    }
}

// ---------------------------------------------------------------------------
// Kernel B: swapped-operand MFMA flash attention per (patch, head).
// 8 waves x 32 q-rows. Output: plain bf16 (u16) via per-wave LDS transpose.
// ---------------------------------------------------------------------------
#define LDSK 0
#define LDSV 8192
#define CPKO 16384
#define RPEO 17408
#define SMEMSZ 18432          // epilogue: 8 waves x [16][72] u16 = 2304 B each

__global__ __launch_bounds__(512, 4) void attn_mfma(
    const u16* __restrict__ q_s, const u16* __restrict__ k_s,
    const u16* __restrict__ vt_s, const unsigned* __restrict__ cpk_g,
    const float* __restrict__ rpe_table, u16* __restrict__ oa16)
{
    __shared__ __align__(16) unsigned char smem[SMEMSZ];
    unsigned* cpk  = (unsigned*)&smem[CPKO];
    float*    rpes = (float*)&smem[RPEO];

    const int t    = threadIdx.x;
    const int p    = blockIdx.x, h = blockIdx.y;
    const int lane = t & 63, wv = t >> 6;
    const int L    = lane & 15, gq = lane >> 4;
    const int q0   = wv * 32;
    const size_t base = (size_t)(p * NH + h) * KP * DH;

    if (t < KP) cpk[t] = cpk_g[p * KP + t];
    if (t >= KP && t < KP + 3 * RNUM) rpes[t - KP] = rpe_table[(t - KP) * NH + h];
    __syncthreads();

    int qx[2], qy[2], qz[2];
#pragma unroll
    for (int qi = 0; qi < 2; ++qi) {
        unsigned c = cpk[q0 + qi * 16 + L];
        qx[qi] = (int)(c & 1023u);
        qy[qi] = (int)((c >> 10) & 1023u);
        qz[qi] = (int)(c >> 20);
    }

    s16x8 aq[2][2];
#pragma unroll
    for (int qi = 0; qi < 2; ++qi)
#pragma unroll
        for (int ks = 0; ks < 2; ++ks)
            aq[qi][ks] = *(const s16x8*)&q_s[base +
                (size_t)(q0 + qi * 16 + L) * DH + ks * 32 + gq * 8];

    f32x4 oacc[2][4];
#pragma unroll
    for (int qi = 0; qi < 2; ++qi)
#pragma unroll
        for (int nd = 0; nd < 4; ++nd) oacc[qi][nd] = (f32x4)0.f;
    float lsum[2] = {0.f, 0.f};

    const int srow = t >> 3;
    const int sc8  = (t & 7) * 8;

    for (int kb = 0; kb < 4; ++kb) {
        __syncthreads();
        {
            const u16* kg = k_s + base + (size_t)(kb * 64 + srow) * DH + sc8;
            gll16(kg, &smem[LDSK + t * 16]);
            const u16* vg = vt_s + base + (size_t)srow * KP + kb * 64 + sc8;
            gll16(vg, &smem[LDSV + t * 16]);
        }
        __syncthreads();

#pragma unroll
        for (int ki = 0; ki < 4; ++ki) {
            const int krow = ki * 16 + L;
            const int kxor = (krow & 7) << 4;
            s16x8 ak0 = *(const s16x8*)&smem[LDSK + krow * 128 + ((gq * 16) ^ kxor)];
            s16x8 ak1 = *(const s16x8*)&smem[LDSK + krow * 128 + ((64 + gq * 16) ^ kxor)];

            f32x4 sacc[2];
            __builtin_amdgcn_s_setprio(1);
#pragma unroll
            for (int qi = 0; qi < 2; ++qi) {
                sacc[qi] = __builtin_amdgcn_mfma_f32_16x16x32_bf16(
                    ak0, aq[qi][0], (f32x4)0.f, 0, 0, 0);
                sacc[qi] = __builtin_amdgcn_mfma_f32_16x16x32_bf16(
                    ak1, aq[qi][1], sacc[qi], 0, 0, 0);
            }
            __builtin_amdgcn_s_setprio(0);

            u32x4 ck4 = *(const u32x4*)&cpk[kb * 64 + ki * 16 + gq * 4];
            int kx[4], ky[4], kz[4];
#pragma unroll
            for (int j = 0; j < 4; ++j) {
                unsigned c = ck4[j];
                kx[j] = (int)(c & 1023u);
                ky[j] = (int)((c >> 10) & 1023u);
                kz[j] = (int)(c >> 20);
            }

            s16x4 pf[2];
#pragma unroll
            for (int qi = 0; qi < 2; ++qi) {
#pragma unroll
                for (int j = 0; j < 4; ++j) {
                    int rx = qx[qi] - kx[j]; rx = rx < -PB ? -PB : (rx > PB ? PB : rx);
                    int ry = qy[qi] - ky[j]; ry = ry < -PB ? -PB : (ry > PB ? PB : ry);
                    int rz = qz[qi] - kz[j]; rz = rz < -PB ? -PB : (rz > PB ? PB : rz);
                    float sv = sacc[qi][j] + rpes[rx + PB]
                             + rpes[RNUM + ry + PB] + rpes[2 * RNUM + rz + PB];
                    float pe = __expf(sv);
                    lsum[qi] += pe;
                    pf[qi][j] = (short)f2b(pe);
                }
            }

            __builtin_amdgcn_s_setprio(1);
#pragma unroll
            for (int nd = 0; nd < 4; ++nd) {
                int d = nd * 16 + L;
                s16x4 vf = *(const s16x4*)&smem[LDSV + d * 128 +
                    (((ki * 16 + gq * 4) * 2) ^ ((d & 7) << 4))];
#pragma unroll
                for (int qi = 0; qi < 2; ++qi)
                    oacc[qi][nd] = __builtin_amdgcn_mfma_f32_16x16x16bf16_1k(
                        pf[qi], vf, oacc[qi][nd], 0, 0, 0);
            }
            __builtin_amdgcn_s_setprio(0);
        }
    }

    float linv[2];
#pragma unroll
    for (int qi = 0; qi < 2; ++qi) {
        float l2 = lsum[qi];
        l2 += __shfl_xor(l2, 16);
        l2 += __shfl_xor(l2, 32);
        linv[qi] = 1.f / l2;
    }

    // staging dead; per-wave [16][72] u16 transpose buffer, then full-line stores
    __syncthreads();
    u16* ot = (u16*)&smem[wv * 2304];
#pragma unroll
    for (int qi = 0; qi < 2; ++qi) {
#pragma unroll
        for (int reg = 0; reg < 4; ++reg) {
            float li = __shfl(linv[qi], gq * 4 + reg);
#pragma unroll
            for (int nd = 0; nd < 4; ++nd)
                ot[(gq * 4 + reg) * 72 + nd * 16 + L] = f2b(oacc[qi][nd][reg] * li);
        }
#pragma unroll
        for (int s = 0; s < 4; ++s) {
            int r = s * 4 + (lane >> 4);
            int c = (lane & 15) * 4;
            u16x4 a = *(const u16x4*)&ot[r * 72 + c];
            int q = q0 + qi * 16 + r;
            *(u16x4*)&oa16[(size_t)(p * KP + q) * CCH + h * DH + c] = a;
        }
    }
}

// ---------------------------------------------------------------------------
// Kernel C: proj GEMM: out = A16 @ (Bh+Bl)^T + bias (2-term, A plain bf16).
// BK=64, 48 KB LDS -> (256,3). XCD swizzle, chunk-XOR source-swizzle.
// ---------------------------------------------------------------------------
__global__ __launch_bounds__(256, 3) void gemm_proj(
    const u16* __restrict__ A16,
    const u16* __restrict__ Bh, const u16* __restrict__ Bl,
    const float* __restrict__ bias, const int* __restrict__ order,
    float* __restrict__ out)
{
    __shared__ __align__(16) unsigned char smemP[49152];   // 48 KB
    u16* LA  = (u16*)smemP;                 // 16 KB
    u16* LBh = (u16*)&smemP[16384];         // 16 KB
    u16* LBl = (u16*)&smemP[32768];         // 16 KB

    const int t = threadIdx.x;
    const int lane = t & 63, wv = t >> 6;
    const int L = lane & 15, gq = lane >> 4;
    const int wr = wv >> 1, wc = wv & 1;

    const int orig = blockIdx.y * 3 + blockIdx.x;
    const int swz  = (orig & 7) * 192 + (orig >> 3);        // bijective (1536%8==0)
    const int n0 = (swz % 3) * 128;
    const int m0 = (swz / 3) * 128;

    f32x4 acc[4][4];
#pragma unroll
    for (int mi = 0; mi < 4; ++mi)
#pragma unroll
        for (int ni = 0; ni < 4; ++ni) acc[mi][ni] = (f32x4)0.f;

    for (int kc = 0; kc < K1; kc += 64) {
        __syncthreads();
#pragma unroll
        for (int i = 0; i < 4; ++i) {
            int ci = i * 256 + t;
            int r = ci >> 3, j = ci & 7;
            int c8 = (j ^ (r & 7)) * 8;
            gll16(A16 + (size_t)(m0 + r) * K1 + kc + c8, LA + ci * 8);
            size_t gb = (size_t)(n0 + r) * K1 + kc + c8;
            gll16(Bh + gb, LBh + ci * 8);
            gll16(Bl + gb, LBl + ci * 8);
        }
        __syncthreads();
#pragma unroll
        for (int ks = 0; ks < 2; ++ks) {
            s16x8 fah[4], fbh[4], fbl[4];
#pragma unroll
            for (int x = 0; x < 4; ++x) {
                int arow = wr * 64 + x * 16 + L;
                int brow = wc * 64 + x * 16 + L;
                int ka  = ((ks * 4 + gq) ^ (arow & 7)) * 8;
                int kb2 = ((ks * 4 + gq) ^ (brow & 7)) * 8;
                fah[x] = *(const s16x8*)&LA[arow * 64 + ka];
                fbh[x] = *(const s16x8*)&LBh[brow * 64 + kb2];
                fbl[x] = *(const s16x8*)&LBl[brow * 64 + kb2];
            }
#pragma unroll
            for (int mi = 0; mi < 4; ++mi)
#pragma unroll
                for (int ni = 0; ni < 4; ++ni) {
                    acc[mi][ni] = __builtin_amdgcn_mfma_f32_16x16x32_bf16(
                        fah[mi], fbh[ni], acc[mi][ni], 0, 0, 0);
                    acc[mi][ni] = __builtin_amdgcn_mfma_f32_16x16x32_bf16(
                        fah[mi], fbl[ni], acc[mi][ni], 0, 0, 0);
                }
        }
    }

    float bfrag[4];
#pragma unroll
    for (int ni = 0; ni < 4; ++ni) bfrag[ni] = bias[n0 + wc * 64 + ni * 16 + L];

    // LDS-transpose epilogue (staging dead): full-line scattered stores.
    __syncthreads();
    float* otp = (float*)smemP + wv * 1088;   // [16][68] f32 per wave (17.4 KB)
#pragma unroll
    for (int mi = 0; mi < 4; ++mi) {
#pragma unroll
        for (int reg = 0; reg < 4; ++reg)
#pragma unroll
            for (int ni = 0; ni < 4; ++ni)
                otp[(gq * 4 + reg) * 68 + ni * 16 + L] = acc[mi][ni][reg] + bfrag[ni];
#pragma unroll
        for (int s = 0; s < 4; ++s) {
            int r = s * 4 + (lane >> 4);
            int c = (lane & 15) * 4;
            f32x4 a = *(const f32x4*)&otp[r * 68 + c];
            int j = m0 + wr * 64 + mi * 16 + r;
            float* dst = out + (size_t)order[j] * CCH + n0 + wc * 64 + c;
            *(f32x4*)dst = a;
        }
        __syncthreads();
    }
}

// ---------------------------------------------------------------------------
extern "C" void kernel_launch(void* const* d_in, const int* in_sizes, int n_in,
                              void* d_out, int out_size, void* d_ws, size_t ws_size,
                              hipStream_t stream) {
    const float* feat      = (const float*)d_in[0];
    const float* qkv_w     = (const float*)d_in[1];
    const float* qkv_b     = (const float*)d_in[2];
    const float* proj_w    = (const float*)d_in[3];
    const float* proj_b    = (const float*)d_in[4];
    const float* rpe_table = (const float*)d_in[5];
    const int*   order     = (const int*)d_in[6];
    const int*   gcoord    = (const int*)d_in[8];
    float* out = (float*)d_out;

    const size_t NC = (size_t)NPTS * CCH;
    u16* fh   = (u16*)d_ws;
    u16* qwh  = fh + NC;
    u16* pwh  = qwh + (size_t)1152 * 384;
    u16* pwl  = pwh + (size_t)384 * 384;
    u16* qs   = pwl + (size_t)384 * 384;
    u16* ks   = qs + NC;
    u16* vts  = ks + NC;
    u16* oa16 = vts + NC;
    unsigned* cpk_g = (unsigned*)(oa16 + NC);

    cast_bf16<<<(1152 * 384 / 4 + 255) / 256, 256, 0, stream>>>(qkv_w, qwh, 1152 * 384 / 4);
    split_arr<<<(384 * 384 / 4 + 255) / 256, 256, 0, stream>>>(proj_w, pwh, pwl, 384 * 384 / 4);
    gather_h<<<NPTS * 96 / 256, 256, 0, stream>>>(feat, order, fh);
    pack_coords<<<NPTS / 256, 256, 0, stream>>>(order, gcoord, cpk_g);

    gemm_qkv<<<dim3(9, NPTS / 128), 256, 0, stream>>>(
        fh, qwh, qkv_b, qs, ks, vts);
    attn_mfma<<<dim3(NPATCH, NH), 512, 0, stream>>>(
        qs, ks, vts, cpk_g, rpe_table, oa16);
    gemm_proj<<<dim3(3, NPTS / 128), 256, 0, stream>>>(
        oa16, pwh, pwl, proj_b, order, out);
}